// Round 14
// baseline (520.955 us; speedup 1.0000x reference)
//
#include <hip/hip_runtime.h>
#include <hip/hip_bf16.h>

#define NPOS 784
#define WDIM 28

typedef short    bf16x8 __attribute__((ext_vector_type(8)));
typedef _Float16 f16x8  __attribute__((ext_vector_type(8)));
typedef float    f32x4  __attribute__((ext_vector_type(4)));

__device__ __forceinline__ unsigned short f2bf(float f) {
    union { float f; unsigned int u; } v; v.f = f;
    unsigned int r = v.u + 0x7fffu + ((v.u >> 16) & 1u);
    return (unsigned short)(r >> 16);
}

// ---------------- kernel 0: embedding-MLP tables (block-invariant) ----------------
__global__ __launch_bounds__(256) void embed_kernel(
    const float* __restrict__ rw1, const float* __restrict__ rb1,
    const float* __restrict__ rga, const float* __restrict__ rbe,
    const float* __restrict__ rw2, const float* __restrict__ rb2,
    const float* __restrict__ cw1, const float* __restrict__ cb1,
    const float* __restrict__ cga, const float* __restrict__ cbe,
    const float* __restrict__ cw2, const float* __restrict__ cb2,
    float* __restrict__ Etr, float* __restrict__ Etc)
{
    int t = threadIdx.x;
    int d = -1;
    const float *w1 = rw1, *b1 = rb1, *ga = rga, *be = rbe, *w2 = rw2, *b2 = rb2;
    float* E = Etr;
    if (t < 110) { d = t; }
    else if (t >= 128 && t < 238) { d = t - 128; w1 = cw1; b1 = cb1; ga = cga; be = cbe; w2 = cw2; b2 = cb2; E = Etc; }
    if (d < 0) return;
    float u = (d < 55) ? (-1.0f + (float)d * (2.0f / 54.0f))
                       : -(-1.0f + (float)(d - 55) * (2.0f / 54.0f));
    float hb[16], mu = 0.0f;
#pragma unroll
    for (int c = 0; c < 16; ++c) { hb[c] = u * w1[c] + b1[c]; mu += hb[c]; }
    mu *= (1.0f / 16.0f);
    float var = 0.0f;
#pragma unroll
    for (int c = 0; c < 16; ++c) { float dv = hb[c] - mu; var += dv * dv; }
    var *= (1.0f / 16.0f);
    float rstd = rsqrtf(var + 1e-5f);
#pragma unroll
    for (int c = 0; c < 16; ++c) {
        float hn = ga[c] * (hb[c] - mu) * rstd + be[c];
        hb[c] = hn / (1.0f + __expf(-hn));
    }
#pragma unroll
    for (int m = 0; m < 8; ++m) {
        float e = b2[m];
#pragma unroll
        for (int c = 0; c < 16; ++c) e += hb[c] * w2[m * 16 + c];
        E[m * 110 + d] = e;                          // transposed [m][110]
    }
}

// ---------------- kernel 1: qkv + MFMA-fragment prestage + out bias-init ----------------
// Q fp32 [bh][ij][16m] (for rotation-table build). QA/KB bf16 and VB f16 are
// written directly in MFMA fragment layouts so the attention kernel loads
// fragments with single dwordx4's.
__global__ __launch_bounds__(256) void qkv_kernel(
    const float* __restrict__ x,
    const float* __restrict__ wq, const float* __restrict__ bq,
    const float* __restrict__ wk, const float* __restrict__ bk,
    const float* __restrict__ wv, const float* __restrict__ bv,
    const float* __restrict__ b_out,
    float* __restrict__ Q, unsigned short* __restrict__ QA,
    unsigned short* __restrict__ KB, _Float16* __restrict__ VB,
    float* __restrict__ out)
{
    int idx = blockIdx.x * 256 + threadIdx.x;        // covers exactly 401408
    int ij = idx % NPOS;
    int oc = (idx / NPOS) & 127;
    int b  = idx / (NPOS * 128);

    float x0 = x[(b * 3 + 0) * NPOS + ij];
    float x1 = x[(b * 3 + 1) * NPOS + ij];
    float x2 = x[(b * 3 + 2) * NPOS + ij];

    float q = bq[oc] + wq[oc*3+0]*x0 + wq[oc*3+1]*x1 + wq[oc*3+2]*x2;
    float k = bk[oc] + wk[oc*3+0]*x0 + wk[oc*3+1]*x1 + wk[oc*3+2]*x2;
    float v = bv[oc] + wv[oc*3+0]*x0 + wv[oc*3+1]*x1 + wv[oc*3+2]*x2;

    int m = oc >> 3, h = oc & 7;                     // oc = m*HEADS + h
    int bh = b * 8 + h;
    Q[((size_t)bh * NPOS + ij) * 16 + m] = q;

    const float scale = 0.57735026918962576f;        // 1/sqrt(CIN=3)
    int qt = ij >> 4, qn = ij & 15;                  // 16-element tile/block index
    int quad = m >> 3, j = m & 7;
    // A-frag (content): A[i=q(lane&15)][k=m(quad*8+j)], quads 0-1 only
    QA[(((size_t)bh * 49 + qt) * 32 + quad * 16 + qn) * 8 + j] = f2bf(q * scale);
    // B-frag (content): B[k=m][n=key(lane&15)]
    KB[(((size_t)bh * 49 + qt) * 32 + quad * 16 + qn) * 8 + j] = f2bf(k);
    // B-frag (PV, f16): B[k=key(quad*8+j of 32-chunk)][n=m(lane&15)]
    int kb = ij >> 5, ko = ij & 31;
    VB[(((size_t)bh * 25 + kb) * 64 + (ko >> 3) * 16 + m) * 8 + (ko & 7)] = (_Float16)v;

    // bias-init the atomic-accumulation output
    for (int e = idx; e < 4 * 64 * 4 * NPOS; e += 401408) {
        int o = (e / (4 * NPOS)) & 63;
        out[e] = b_out[o];
    }
}

// ---------------- kernel 2: MFMA attention ----------------
// Block = (bh, 16-query tile): 1568 blocks x 4 waves. Waves split the 784
// keys in 32-key chunks round-robin. Content via bf16 MFMA (2 passes:
// max, then ec=exp(c-max) staged f16 in A-layout). PV: per chunk, A-frags
// for all 4 rotations built in registers (ec * exp'ed rot terms), f16 MFMA
// vs prestaged V B-frags; ones-B MFMA produces softmax sums for free.
__global__ __launch_bounds__(256, 4) void attn_kernel(
    const float* __restrict__ Q, const unsigned short* __restrict__ QA,
    const unsigned short* __restrict__ KB, const _Float16* __restrict__ VB,
    const float* __restrict__ Etr, const float* __restrict__ Etc,
    const float* __restrict__ w_out, float* __restrict__ out)
{
    __shared__ __align__(16) char smem[44032];       // RtE(14336) + ecT(29696); comb overlays
    __shared__ float ovs2[16 * 4 * 16];              // [q][g][m]
    __shared__ float rmax[64];
    __shared__ float maxbuf[16 * 4];

    float*    RtE  = (float*)smem;                   // [16 q][56 d][4] fp32 (exp'ed)
    _Float16* ecT  = (_Float16*)(smem + 14336);      // [4 w][16 q][232 k]
    float*    comb = (float*)smem;                   // [4 w][64 lane][32] (after PV)

    const int t    = threadIdx.x;
    const int wv   = t >> 6, lane = t & 63;
    const int quad = lane >> 4;
    const int bh   = blockIdx.x & 31;                // round-robin XCDs over (b,h)
    const int qt   = blockIdx.x >> 5;
    const int b    = bh >> 3, h = bh & 7;
    const float scale = 0.57735026918962576f;

    // ---- rotation tables: raw -> per-(q,comp) max -> exp'ed, pad row zeroed ----
    for (int idx = t; idx < 880; idx += 256) {
        int q = idx / 55, d = idx - q * 55;
        const float* Qrow = Q + ((size_t)bh * NPOS + qt * 16 + q) * 16;
        float ar = 0, ac = 0, ar5 = 0, ac5 = 0;
#pragma unroll
        for (int mm = 0; mm < 8; ++mm) {
            float ql = Qrow[mm], qh = Qrow[8 + mm];
            ar  += ql * Etr[mm * 110 + d];  ar5 += ql * Etr[mm * 110 + d + 55];
            ac  += qh * Etc[mm * 110 + d];  ac5 += qh * Etc[mm * 110 + d + 55];
        }
        *(float4*)&RtE[(q * 56 + d) * 4] =
            make_float4(ar * scale, ac * scale, ar5 * scale, ac5 * scale);
    }
    __syncthreads();
    if (t < 64) {
        int q = t >> 2, cc = t & 3;
        float mx = -3.0e38f;
        for (int d = 0; d < 55; ++d) mx = fmaxf(mx, RtE[(q * 56 + d) * 4 + cc]);
        rmax[t] = mx;
    }
    __syncthreads();
    for (int idx = t; idx < 880; idx += 256) {
        int q = idx / 55, d = idx - q * 55;
#pragma unroll
        for (int cc = 0; cc < 4; ++cc)
            RtE[(q * 56 + d) * 4 + cc] = __expf(RtE[(q * 56 + d) * 4 + cc] - rmax[q * 4 + cc]);
    }
    if (t < 64) RtE[((t >> 2) * 56 + 55) * 4 + (t & 3)] = 0.0f;  // zero d=55 pad
    __syncthreads();

    // ---- content A-frag (Q-tile, shared by all blocks' MFMAs) ----
    bf16x8 zero8 = {};
    bf16x8 aq = zero8;
    if (lane < 32) aq = *(const bf16x8*)(QA + (((size_t)bh * 49 + qt) * 32 + lane) * 8);

    const int nlc = (wv == 0) ? 7 : 6;               // 32-key chunks owned (c = lc*4+wv)

    // ---- pass 1: per-query content max over this wave's keys ----
    float mc0 = -3.0e38f, mc1 = -3.0e38f, mc2 = -3.0e38f, mc3 = -3.0e38f;
    for (int bl = 0; bl < 2 * nlc; ++bl) {
        int kb = 2 * ((bl >> 1) * 4 + wv) + (bl & 1);
        if (kb > 48) continue;
        bf16x8 bk = zero8;
        if (lane < 32) bk = *(const bf16x8*)(KB + (((size_t)bh * 49 + kb) * 32 + lane) * 8);
        f32x4 cz = {0.f, 0.f, 0.f, 0.f};
        f32x4 d = __builtin_amdgcn_mfma_f32_16x16x32_bf16(aq, bk, cz, 0, 0, 0);
        mc0 = fmaxf(mc0, d[0]); mc1 = fmaxf(mc1, d[1]);
        mc2 = fmaxf(mc2, d[2]); mc3 = fmaxf(mc3, d[3]);
    }
#pragma unroll
    for (int off = 1; off < 16; off <<= 1) {
        mc0 = fmaxf(mc0, __shfl_xor(mc0, off, 64));
        mc1 = fmaxf(mc1, __shfl_xor(mc1, off, 64));
        mc2 = fmaxf(mc2, __shfl_xor(mc2, off, 64));
        mc3 = fmaxf(mc3, __shfl_xor(mc3, off, 64));
    }
    if ((lane & 15) == 0) {
        maxbuf[(quad * 4 + 0) * 4 + wv] = mc0;
        maxbuf[(quad * 4 + 1) * 4 + wv] = mc1;
        maxbuf[(quad * 4 + 2) * 4 + wv] = mc2;
        maxbuf[(quad * 4 + 3) * 4 + wv] = mc3;
    }
    __syncthreads();
    mc0 = fmaxf(fmaxf(maxbuf[(quad*4+0)*4+0], maxbuf[(quad*4+0)*4+1]),
                fmaxf(maxbuf[(quad*4+0)*4+2], maxbuf[(quad*4+0)*4+3]));
    mc1 = fmaxf(fmaxf(maxbuf[(quad*4+1)*4+0], maxbuf[(quad*4+1)*4+1]),
                fmaxf(maxbuf[(quad*4+1)*4+2], maxbuf[(quad*4+1)*4+3]));
    mc2 = fmaxf(fmaxf(maxbuf[(quad*4+2)*4+0], maxbuf[(quad*4+2)*4+1]),
                fmaxf(maxbuf[(quad*4+2)*4+2], maxbuf[(quad*4+2)*4+3]));
    mc3 = fmaxf(fmaxf(maxbuf[(quad*4+3)*4+0], maxbuf[(quad*4+3)*4+1]),
                fmaxf(maxbuf[(quad*4+3)*4+2], maxbuf[(quad*4+3)*4+3]));

    // ---- pass 2: ec = exp(c - maxc) -> f16 in A-layout tile [q][k_local] ----
    _Float16* myT = ecT + (size_t)wv * 16 * 232;
    for (int bl = 0; bl < 2 * nlc; ++bl) {
        int kb = 2 * ((bl >> 1) * 4 + wv) + (bl & 1);
        if (kb > 48) continue;
        bf16x8 bk = zero8;
        if (lane < 32) bk = *(const bf16x8*)(KB + (((size_t)bh * 49 + kb) * 32 + lane) * 8);
        f32x4 cz = {0.f, 0.f, 0.f, 0.f};
        f32x4 d = __builtin_amdgcn_mfma_f32_16x16x32_bf16(aq, bk, cz, 0, 0, 0);
        int klocal = (bl >> 1) * 32 + (bl & 1) * 16 + (lane & 15);
        myT[(quad * 4 + 0) * 232 + klocal] = (_Float16)__expf(d[0] - mc0);
        myT[(quad * 4 + 1) * 232 + klocal] = (_Float16)__expf(d[1] - mc1);
        myT[(quad * 4 + 2) * 232 + klocal] = (_Float16)__expf(d[2] - mc2);
        myT[(quad * 4 + 3) * 232 + klocal] = (_Float16)__expf(d[3] - mc3);
    }
    if (wv == 0) {                                   // zero pad keys 784..799 (chunk 24)
#pragma unroll
        for (int r = 0; r < 4; ++r)
            myT[(quad * 4 + r) * 232 + 208 + (lane & 15)] = (_Float16)0.0f;
    }
    // same-wave LDS write->read is in-order: no barrier needed before PV

    // ---- PV: per chunk, build 4 rotation A-frags in registers, f16 MFMA ----
    const int q_a  = lane & 15;
    const int ij_a = qt * 16 + q_a;
    const int iq_a = (ij_a * 2341) >> 16;
    const int jq_a = ij_a - iq_a * WDIM;
    f16x8 bones;
#pragma unroll
    for (int j = 0; j < 8; ++j) bones[j] = (_Float16)1.0f;
    f32x4 acc0 = {0,0,0,0}, acc1 = {0,0,0,0}, acc2 = {0,0,0,0}, acc3 = {0,0,0,0};
    f32x4 ps0  = {0,0,0,0}, ps1  = {0,0,0,0}, ps2  = {0,0,0,0}, ps3  = {0,0,0,0};
    const _Float16* myec = myT + q_a * 232;
    for (int lc = 0; lc < nlc; ++lc) {
        int c = lc * 4 + wv;
        f16x8 bv = *(const f16x8*)(VB + (((size_t)bh * 25 + c) * 64 + lane) * 8);
        f16x8 ef = *(const f16x8*)(myec + lc * 32 + quad * 8);
        f16x8 a0, a1, a2, a3;
#pragma unroll
        for (int j = 0; j < 8; ++j) {
            int key = c * 32 + quad * 8 + j;
            int rk  = (key * 2341) >> 16;            // key / 28 (valid to 799)
            int ck  = key - rk * WDIM;
            float ec = (float)ef[j];
            float4 er = *(const float4*)&RtE[(q_a * 56 + rk - iq_a + 27) * 4];
            float4 el = *(const float4*)&RtE[(q_a * 56 + ck - jq_a + 27) * 4];
            a0[j] = (_Float16)(ec * er.x * el.y);
            a1[j] = (_Float16)(ec * er.y * el.z);
            a2[j] = (_Float16)(ec * er.z * el.w);
            a3[j] = (_Float16)(ec * er.w * el.x);
        }
        acc0 = __builtin_amdgcn_mfma_f32_16x16x32_f16(a0, bv, acc0, 0, 0, 0);
        acc1 = __builtin_amdgcn_mfma_f32_16x16x32_f16(a1, bv, acc1, 0, 0, 0);
        acc2 = __builtin_amdgcn_mfma_f32_16x16x32_f16(a2, bv, acc2, 0, 0, 0);
        acc3 = __builtin_amdgcn_mfma_f32_16x16x32_f16(a3, bv, acc3, 0, 0, 0);
        ps0  = __builtin_amdgcn_mfma_f32_16x16x32_f16(a0, bones, ps0, 0, 0, 0);
        ps1  = __builtin_amdgcn_mfma_f32_16x16x32_f16(a1, bones, ps1, 0, 0, 0);
        ps2  = __builtin_amdgcn_mfma_f32_16x16x32_f16(a2, bones, ps2, 0, 0, 0);
        ps3  = __builtin_amdgcn_mfma_f32_16x16x32_f16(a3, bones, ps3, 0, 0, 0);
    }

    // ---- combine wave partials (comb overlays RtE/ecT after barrier) ----
    __syncthreads();
    {
        float* myc = comb + ((size_t)wv * 64 + lane) * 32;
        *(f32x4*)(myc +  0) = acc0; *(f32x4*)(myc +  4) = acc1;
        *(f32x4*)(myc +  8) = acc2; *(f32x4*)(myc + 12) = acc3;
        *(f32x4*)(myc + 16) = ps0;  *(f32x4*)(myc + 20) = ps1;
        *(f32x4*)(myc + 24) = ps2;  *(f32x4*)(myc + 28) = ps3;
    }
    __syncthreads();
    if (wv == 0) {
#pragma unroll
        for (int g = 0; g < 4; ++g) {
            f32x4 A = {0,0,0,0}, P = {0,0,0,0};
#pragma unroll
            for (int w = 0; w < 4; ++w) {
                const float* cw_ = comb + ((size_t)w * 64 + lane) * 32;
                A += *(const f32x4*)(cw_ + g * 4);
                P += *(const f32x4*)(cw_ + 16 + g * 4);
            }
#pragma unroll
            for (int r = 0; r < 4; ++r)
                ovs2[((quad * 4 + r) * 4 + g) * 16 + (lane & 15)] = A[r] / P[r];
        }
    }
    __syncthreads();

    // ---- projection partial for this head; thread = (o, g); atomicAdd ----
    {
        int o = t >> 2, g = t & 3;
        float wreg[16];
#pragma unroll
        for (int m = 0; m < 16; ++m) wreg[m] = w_out[o * 128 + m * 8 + h];
        float* obase = out + ((size_t)((b * 64 + o) * 4 + g)) * NPOS + qt * 16;
        for (int qq = 0; qq < 16; ++qq) {
            float a = 0.0f;
#pragma unroll
            for (int m = 0; m < 16; ++m) a += wreg[m] * ovs2[(qq * 4 + g) * 16 + m];
            atomicAdd(obase + qq, a);
        }
    }
}

extern "C" void kernel_launch(void* const* d_in, const int* in_sizes, int n_in,
                              void* d_out, int out_size, void* d_ws, size_t ws_size,
                              hipStream_t stream)
{
    const float* x     = (const float*)d_in[0];
    const float* wq    = (const float*)d_in[1];
    const float* bq    = (const float*)d_in[2];
    const float* wk    = (const float*)d_in[3];
    const float* bk    = (const float*)d_in[4];
    const float* wv    = (const float*)d_in[5];
    const float* bv    = (const float*)d_in[6];
    const float* w_out = (const float*)d_in[7];
    const float* b_out = (const float*)d_in[8];
    const float* rw1 = (const float*)d_in[9];
    const float* rb1 = (const float*)d_in[10];
    const float* rga = (const float*)d_in[11];
    const float* rbe = (const float*)d_in[12];
    const float* rw2 = (const float*)d_in[13];
    const float* rb2 = (const float*)d_in[14];
    const float* cw1 = (const float*)d_in[15];
    const float* cb1 = (const float*)d_in[16];
    const float* cga = (const float*)d_in[17];
    const float* cbe = (const float*)d_in[18];
    const float* cw2 = (const float*)d_in[19];
    const float* cb2 = (const float*)d_in[20];
    // d_in[21]/d_in[22] (ridx/cidx) unused: closed-form rotation indices.

    // ws layout (3.85 MB total, < proven 4.83 MB):
    float* Q   = (float*)d_ws;                       // 401408 f32
    float* Etr = Q + 401408;                         // 880 f32
    float* Etc = Etr + 880;                          // 880 f32
    unsigned short* QA = (unsigned short*)(Etc + 880);   // 401408 u16 (bf16 A-frags)
    unsigned short* KB = QA + 401408;                    // 401408 u16 (bf16 B-frags)
    _Float16*       VB = (_Float16*)(KB + 401408);       // 409600 f16 (B-frags, chunk 24 tail unused)

    embed_kernel<<<1, 256, 0, stream>>>(rw1, rb1, rga, rbe, rw2, rb2,
                                        cw1, cb1, cga, cbe, cw2, cb2, Etr, Etc);
    qkv_kernel<<<1568, 256, 0, stream>>>(x, wq, bq, wk, bk, wv, bv, b_out,
                                         Q, QA, KB, VB, (float*)d_out);
    attn_kernel<<<32 * 49, 256, 0, stream>>>(Q, QA, KB, VB, Etr, Etc,
                                             w_out, (float*)d_out);
}

// Round 15
// 305.338 us; speedup vs baseline: 1.7062x; 1.7062x over previous
//
#include <hip/hip_runtime.h>
#include <hip/hip_bf16.h>
#include <hip/hip_fp16.h>

#define NPOS 784
#define WDIM 28

// ---------------- kernel 1: merged embed + qkv + out bias-init ----------------
// Blocks 0..1567: fused 1x1-conv q/k/v (fp32, [bh][kl][m]) + bias-init out.
// Block 1568: embedding-MLP tables Etr/Etc (block-invariant, transposed [m][110]).
__global__ __launch_bounds__(256) void prep_kernel(
    const float* __restrict__ x,
    const float* __restrict__ wq, const float* __restrict__ bq,
    const float* __restrict__ wk, const float* __restrict__ bk,
    const float* __restrict__ wv, const float* __restrict__ bv,
    const float* __restrict__ b_out,
    const float* __restrict__ rw1, const float* __restrict__ rb1,
    const float* __restrict__ rga, const float* __restrict__ rbe,
    const float* __restrict__ rw2, const float* __restrict__ rb2,
    const float* __restrict__ cw1, const float* __restrict__ cb1,
    const float* __restrict__ cga, const float* __restrict__ cbe,
    const float* __restrict__ cw2, const float* __restrict__ cb2,
    float* __restrict__ Q, float* __restrict__ K, float* __restrict__ V,
    float* __restrict__ Etr, float* __restrict__ Etc,
    float* __restrict__ out)
{
    if (blockIdx.x == 1568) {                        // ---- embed path ----
        int t = threadIdx.x;
        int d = -1;
        const float *w1 = rw1, *b1 = rb1, *ga = rga, *be = rbe, *w2 = rw2, *b2 = rb2;
        float* E = Etr;
        if (t < 110) { d = t; }
        else if (t >= 128 && t < 238) { d = t - 128; w1 = cw1; b1 = cb1; ga = cga; be = cbe; w2 = cw2; b2 = cb2; E = Etc; }
        if (d < 0) return;
        float u = (d < 55) ? (-1.0f + (float)d * (2.0f / 54.0f))
                           : -(-1.0f + (float)(d - 55) * (2.0f / 54.0f));
        float hb[16], mu = 0.0f;
#pragma unroll
        for (int c = 0; c < 16; ++c) { hb[c] = u * w1[c] + b1[c]; mu += hb[c]; }
        mu *= (1.0f / 16.0f);
        float var = 0.0f;
#pragma unroll
        for (int c = 0; c < 16; ++c) { float dv = hb[c] - mu; var += dv * dv; }
        var *= (1.0f / 16.0f);
        float rstd = rsqrtf(var + 1e-5f);
#pragma unroll
        for (int c = 0; c < 16; ++c) {
            float hn = ga[c] * (hb[c] - mu) * rstd + be[c];
            hb[c] = hn / (1.0f + __expf(-hn));
        }
#pragma unroll
        for (int m = 0; m < 8; ++m) {
            float e = b2[m];
#pragma unroll
            for (int c = 0; c < 16; ++c) e += hb[c] * w2[m * 16 + c];
            E[m * 110 + d] = e;
        }
        return;
    }

    // ---- qkv path ----
    int idx = blockIdx.x * 256 + threadIdx.x;        // covers exactly 401408
    int ij = idx % NPOS;
    int oc = (idx / NPOS) & 127;
    int b  = idx / (NPOS * 128);

    float x0 = x[(b * 3 + 0) * NPOS + ij];
    float x1 = x[(b * 3 + 1) * NPOS + ij];
    float x2 = x[(b * 3 + 2) * NPOS + ij];

    float q = bq[oc] + wq[oc*3+0]*x0 + wq[oc*3+1]*x1 + wq[oc*3+2]*x2;
    float k = bk[oc] + wk[oc*3+0]*x0 + wk[oc*3+1]*x1 + wk[oc*3+2]*x2;
    float v = bv[oc] + wv[oc*3+0]*x0 + wv[oc*3+1]*x1 + wv[oc*3+2]*x2;

    int m = oc >> 3, h = oc & 7;                     // oc = m*HEADS + h
    int dst = ((b * 8 + h) * NPOS + ij) * 16 + m;
    Q[dst] = q; K[dst] = k; V[dst] = v;

    for (int e = idx; e < 4 * 64 * 4 * NPOS; e += 401408) {
        int o = (e / (4 * NPOS)) & 63;
        out[e] = b_out[o];
    }
}

// ---------------- kernel 2: attention, one head per wave (r13 base) ----------------
// Grid = (b, ij, head-group): 6272 blocks. New: pass B computes each (key,g)
// probability ONCE (content kept in registers), stores f16x2 p-pairs in LDS;
// PV reads 2 broadcast b32s per key (was 2xb128 + b32 + 8 mults, x4 redundant).
__global__ __launch_bounds__(256, 6) void attn_kernel(
    const float* __restrict__ Q, const float* __restrict__ K, const float* __restrict__ V,
    const float* __restrict__ Etr, const float* __restrict__ Etc,
    const float* __restrict__ w_out,
    float* __restrict__ out)
{
    __shared__ float4       RtE[4][56];              // exp'ed rotation terms per wave
    __shared__ unsigned int ptile[4][1600];          // [wave][pair*800 + (k&15)*50 + (k>>4)]
    __shared__ float        ovs[4][4][16];           // [wave(h4)][g][m]

    const int t    = threadIdx.x;
    const int wave = t >> 6, lane = t & 63;
    // XCD-aware decode (r13): low bits round-robin (b, ij-parity) across XCDs
    const int bid = blockIdx.x;
    const int b   = (bid >> 1) & 3;
    const int r   = bid >> 3;
    const int hg  = r & 1;
    const int ij  = (r >> 1) * 2 + (bid & 1);
    const int iq  = ij / WDIM, jq = ij % WDIM;
    const int h   = hg * 4 + wave;
    const int bh  = b * 8 + h;
    const float scale = 0.57735026918962576f;        // 1/sqrt(CIN=3)

    // q in registers (wave-uniform loads, L2-hot)
    float q[16];
    {
        const float4* qp = (const float4*)(Q + (size_t)(bh * NPOS + ij) * 16);
        float4 q0 = qp[0], q1 = qp[1], q2 = qp[2], q3 = qp[3];
        q[0]=q0.x; q[1]=q0.y; q[2]=q0.z; q[3]=q0.w;
        q[4]=q1.x; q[5]=q1.y; q[6]=q1.z; q[7]=q1.w;
        q[8]=q2.x; q[9]=q2.y; q[10]=q2.z; q[11]=q2.w;
        q[12]=q3.x; q[13]=q3.y; q[14]=q3.z; q[15]=q3.w;
    }

    // rotation terms from global tables -> exp'ed (r13 verbatim)
    {
        float4 mine = make_float4(-3.0e38f, -3.0e38f, -3.0e38f, -3.0e38f);
        float4 rv   = mine;
        if (lane < 55) {
            float ar = 0, ac = 0, ar5 = 0, ac5 = 0;
#pragma unroll
            for (int mm = 0; mm < 8; ++mm) {
                float ql = q[mm], qh = q[8 + mm];
                ar  += ql * Etr[mm * 110 + lane];
                ar5 += ql * Etr[mm * 110 + lane + 55];
                ac  += qh * Etc[mm * 110 + lane];
                ac5 += qh * Etc[mm * 110 + lane + 55];
            }
            rv = make_float4(ar * scale, ac * scale, ar5 * scale, ac5 * scale);
            mine = rv;
        }
#pragma unroll
        for (int off = 1; off < 64; off <<= 1) {
            mine.x = fmaxf(mine.x, __shfl_xor(mine.x, off, 64));
            mine.y = fmaxf(mine.y, __shfl_xor(mine.y, off, 64));
            mine.z = fmaxf(mine.z, __shfl_xor(mine.z, off, 64));
            mine.w = fmaxf(mine.w, __shfl_xor(mine.w, off, 64));
        }
        if (lane < 55)
            RtE[wave][lane] = make_float4(__expf(rv.x - mine.x), __expf(rv.y - mine.y),
                                          __expf(rv.z - mine.z), __expf(rv.w - mine.w));
    }

    // pass A: content in REGISTERS (no LDS round-trip); track max
    float creg[13];
    float maxc = -3.0e38f;
#pragma unroll
    for (int it = 0; it < 13; ++it) {
        int k = it * 64 + lane;
        creg[it] = 0.0f;
        if (k < NPOS) {
            const float4* kp = (const float4*)(K + (size_t)(bh * NPOS + k) * 16);
            float4 k0 = kp[0], k1 = kp[1], k2 = kp[2], k3 = kp[3];
            float c = q[0]*k0.x + q[1]*k0.y + q[2]*k0.z + q[3]*k0.w
                    + q[4]*k1.x + q[5]*k1.y + q[6]*k1.z + q[7]*k1.w
                    + q[8]*k2.x + q[9]*k2.y + q[10]*k2.z + q[11]*k2.w
                    + q[12]*k3.x + q[13]*k3.y + q[14]*k3.z + q[15]*k3.w;
            creg[it] = c * scale;
            maxc = fmaxf(maxc, creg[it]);
        }
    }
#pragma unroll
    for (int off = 1; off < 64; off <<= 1) maxc = fmaxf(maxc, __shfl_xor(maxc, off, 64));

    // pass B: p computed ONCE per (key,g), packed f16x2 -> LDS
    // (same-wave write->read before PV: in-order, no barrier)
#pragma unroll
    for (int it = 0; it < 13; ++it) {
        int k = it * 64 + lane;
        if (k < NPOS) {
            float ec = __expf(creg[it] - maxc);
            int rk = (k * 2341) >> 16;               // k / 28 (exact for k < 784)
            int ck = k - rk * WDIM;
            float4 er = RtE[wave][rk - iq + 27];
            float4 el = RtE[wave][ck - jq + 27];
            float p0 = ec * er.x * el.y;
            float p1 = ec * er.y * el.z;
            float p2 = ec * er.z * el.w;
            float p3 = ec * er.w * el.x;
            __half2 h01 = __floats2half2_rn(p0, p1);
            __half2 h23 = __floats2half2_rn(p2, p3);
            int slot = (k & 15) * 50 + (k >> 4);
            ptile[wave][slot]       = *(unsigned int*)&h01;
            ptile[wave][800 + slot] = *(unsigned int*)&h23;
        }
    }

    // pass C (PV): lane = (vq = lane>>4, ch = lane&15); keys k = s*16+ch.
    // 2 broadcast b32 LDS reads + 4 cvt + 16 FMA per key.
    {
        const int vq = lane >> 4, ch = lane & 15;
        float acc[4][4];
#pragma unroll
        for (int g = 0; g < 4; ++g)
#pragma unroll
            for (int c = 0; c < 4; ++c) acc[g][c] = 0.0f;
        float ps0 = 0, ps1 = 0, ps2 = 0, ps3 = 0;
#pragma unroll 4
        for (int s = 0; s < 49; ++s) {
            unsigned int ua = ptile[wave][ch * 50 + s];
            unsigned int ub = ptile[wave][800 + ch * 50 + s];
            float2 P01 = __half22float2(*(__half2*)&ua);
            float2 P23 = __half22float2(*(__half2*)&ub);
            float p0 = P01.x, p1 = P01.y, p2 = P23.x, p3 = P23.y;
            ps0 += p0; ps1 += p1; ps2 += p2; ps3 += p3;
            int k = s * 16 + ch;
            float4 v = ((const float4*)(V + (size_t)(bh * NPOS + k) * 16))[vq];
            acc[0][0] += p0*v.x; acc[0][1] += p0*v.y; acc[0][2] += p0*v.z; acc[0][3] += p0*v.w;
            acc[1][0] += p1*v.x; acc[1][1] += p1*v.y; acc[1][2] += p1*v.z; acc[1][3] += p1*v.w;
            acc[2][0] += p2*v.x; acc[2][1] += p2*v.y; acc[2][2] += p2*v.z; acc[2][3] += p2*v.w;
            acc[3][0] += p3*v.x; acc[3][1] += p3*v.y; acc[3][2] += p3*v.z; acc[3][3] += p3*v.w;
        }
        // reduce over the 16 ch lanes (xor stays within each vq group)
#pragma unroll
        for (int off = 1; off < 16; off <<= 1) {
            ps0 += __shfl_xor(ps0, off, 64); ps1 += __shfl_xor(ps1, off, 64);
            ps2 += __shfl_xor(ps2, off, 64); ps3 += __shfl_xor(ps3, off, 64);
#pragma unroll
            for (int g = 0; g < 4; ++g)
#pragma unroll
                for (int c = 0; c < 4; ++c) acc[g][c] += __shfl_xor(acc[g][c], off, 64);
        }
        if (ch == 0) {
            float inv0 = 1.0f / ps0, inv1 = 1.0f / ps1, inv2 = 1.0f / ps2, inv3 = 1.0f / ps3;
#pragma unroll
            for (int c = 0; c < 4; ++c) {
                ovs[wave][0][vq * 4 + c] = acc[0][c] * inv0;
                ovs[wave][1][vq * 4 + c] = acc[1][c] * inv1;
                ovs[wave][2][vq * 4 + c] = acc[2][c] * inv2;
                ovs[wave][3][vq * 4 + c] = acc[3][c] * inv3;
            }
        }
    }
    __syncthreads();                                 // this block's 4 heads ready

    // partial output projection over 4 heads; thread = (o = t>>2, g = t&3)
    {
        int o = t >> 2, g = t & 3;
        float a = 0.0f;
#pragma unroll
        for (int m = 0; m < 16; ++m) {
            float4 w4 = *(const float4*)(w_out + o * 128 + m * 8 + hg * 4);
            a += w4.x * ovs[0][g][m] + w4.y * ovs[1][g][m]
               + w4.z * ovs[2][g][m] + w4.w * ovs[3][g][m];
        }
        atomicAdd(out + ((size_t)(b * 64 + o) * 4 + g) * NPOS + ij, a);
    }
}

extern "C" void kernel_launch(void* const* d_in, const int* in_sizes, int n_in,
                              void* d_out, int out_size, void* d_ws, size_t ws_size,
                              hipStream_t stream)
{
    const float* x     = (const float*)d_in[0];
    const float* wq    = (const float*)d_in[1];
    const float* bq    = (const float*)d_in[2];
    const float* wk    = (const float*)d_in[3];
    const float* bk    = (const float*)d_in[4];
    const float* wv    = (const float*)d_in[5];
    const float* bv    = (const float*)d_in[6];
    const float* w_out = (const float*)d_in[7];
    const float* b_out = (const float*)d_in[8];
    const float* rw1 = (const float*)d_in[9];
    const float* rb1 = (const float*)d_in[10];
    const float* rga = (const float*)d_in[11];
    const float* rbe = (const float*)d_in[12];
    const float* rw2 = (const float*)d_in[13];
    const float* rb2 = (const float*)d_in[14];
    const float* cw1 = (const float*)d_in[15];
    const float* cb1 = (const float*)d_in[16];
    const float* cga = (const float*)d_in[17];
    const float* cbe = (const float*)d_in[18];
    const float* cw2 = (const float*)d_in[19];
    const float* cb2 = (const float*)d_in[20];
    // d_in[21]/d_in[22] (ridx/cidx) unused: closed-form rotation indices.

    float* Q   = (float*)d_ws;               // 3 x 401408 floats = 4.8 MB (proven)
    float* K   = Q + 401408;
    float* V   = K + 401408;
    float* Etr = V + 401408;                 // 880 floats
    float* Etc = Etr + 880;                  // 880 floats

    prep_kernel<<<1569, 256, 0, stream>>>(x, wq, bq, wk, bk, wv, bv, b_out,
                                          rw1, rb1, rga, rbe, rw2, rb2,
                                          cw1, cb1, cga, cbe, cw2, cb2,
                                          Q, K, V, Etr, Etc, (float*)d_out);
    attn_kernel<<<8 * NPOS, 256, 0, stream>>>(
        Q, K, V, Etr, Etc, w_out, (float*)d_out);
}

// Round 16
// 304.881 us; speedup vs baseline: 1.7087x; 1.0015x over previous
//
#include <hip/hip_runtime.h>
#include <hip/hip_bf16.h>
#include <hip/hip_fp16.h>

#define NPOS 784
#define WDIM 28

// ---------------- kernel 1: merged embed + qkv + out bias-init ----------------
// Blocks 0..1567: fused 1x1-conv q/k/v (fp32, [bh][kl][m]) + bias-init out.
// Block 1568: embedding-MLP tables Etr/Etc (block-invariant, transposed [m][110]).
__global__ __launch_bounds__(256) void prep_kernel(
    const float* __restrict__ x,
    const float* __restrict__ wq, const float* __restrict__ bq,
    const float* __restrict__ wk, const float* __restrict__ bk,
    const float* __restrict__ wv, const float* __restrict__ bv,
    const float* __restrict__ b_out,
    const float* __restrict__ rw1, const float* __restrict__ rb1,
    const float* __restrict__ rga, const float* __restrict__ rbe,
    const float* __restrict__ rw2, const float* __restrict__ rb2,
    const float* __restrict__ cw1, const float* __restrict__ cb1,
    const float* __restrict__ cga, const float* __restrict__ cbe,
    const float* __restrict__ cw2, const float* __restrict__ cb2,
    float* __restrict__ Q, float* __restrict__ K, float* __restrict__ V,
    float* __restrict__ Etr, float* __restrict__ Etc,
    float* __restrict__ out)
{
    if (blockIdx.x == 1568) {                        // ---- embed path ----
        int t = threadIdx.x;
        int d = -1;
        const float *w1 = rw1, *b1 = rb1, *ga = rga, *be = rbe, *w2 = rw2, *b2 = rb2;
        float* E = Etr;
        if (t < 110) { d = t; }
        else if (t >= 128 && t < 238) { d = t - 128; w1 = cw1; b1 = cb1; ga = cga; be = cbe; w2 = cw2; b2 = cb2; E = Etc; }
        if (d < 0) return;
        float u = (d < 55) ? (-1.0f + (float)d * (2.0f / 54.0f))
                           : -(-1.0f + (float)(d - 55) * (2.0f / 54.0f));
        float hb[16], mu = 0.0f;
#pragma unroll
        for (int c = 0; c < 16; ++c) { hb[c] = u * w1[c] + b1[c]; mu += hb[c]; }
        mu *= (1.0f / 16.0f);
        float var = 0.0f;
#pragma unroll
        for (int c = 0; c < 16; ++c) { float dv = hb[c] - mu; var += dv * dv; }
        var *= (1.0f / 16.0f);
        float rstd = rsqrtf(var + 1e-5f);
#pragma unroll
        for (int c = 0; c < 16; ++c) {
            float hn = ga[c] * (hb[c] - mu) * rstd + be[c];
            hb[c] = hn / (1.0f + __expf(-hn));
        }
#pragma unroll
        for (int m = 0; m < 8; ++m) {
            float e = b2[m];
#pragma unroll
            for (int c = 0; c < 16; ++c) e += hb[c] * w2[m * 16 + c];
            E[m * 110 + d] = e;
        }
        return;
    }

    // ---- qkv path ----
    int idx = blockIdx.x * 256 + threadIdx.x;        // covers exactly 401408
    int ij = idx % NPOS;
    int oc = (idx / NPOS) & 127;
    int b  = idx / (NPOS * 128);

    float x0 = x[(b * 3 + 0) * NPOS + ij];
    float x1 = x[(b * 3 + 1) * NPOS + ij];
    float x2 = x[(b * 3 + 2) * NPOS + ij];

    float q = bq[oc] + wq[oc*3+0]*x0 + wq[oc*3+1]*x1 + wq[oc*3+2]*x2;
    float k = bk[oc] + wk[oc*3+0]*x0 + wk[oc*3+1]*x1 + wk[oc*3+2]*x2;
    float v = bv[oc] + wv[oc*3+0]*x0 + wv[oc*3+1]*x1 + wv[oc*3+2]*x2;

    int m = oc >> 3, h = oc & 7;                     // oc = m*HEADS + h
    int dst = ((b * 8 + h) * NPOS + ij) * 16 + m;
    Q[dst] = q; K[dst] = k; V[dst] = v;

    for (int e = idx; e < 4 * 64 * 4 * NPOS; e += 401408) {
        int o = (e / (4 * NPOS)) & 63;
        out[e] = b_out[o];
    }
}

// ---------------- kernel 2: attention, one head per wave ----------------
// Grid = (b, ij, head-group): 6272 blocks. r15 base +
// (1) ps accumulated in pass B from register-resident p (kills x4-redundant
//     sums in PV), single 4-value full-wave butterfly;
// (2) p-pairs stored ADJACENT -> pass C reads one ds_read_b64 per key;
// (3) pass C reduction is acc-only (16 values).
__global__ __launch_bounds__(256, 6) void attn_kernel(
    const float* __restrict__ Q, const float* __restrict__ K, const float* __restrict__ V,
    const float* __restrict__ Etr, const float* __restrict__ Etc,
    const float* __restrict__ w_out,
    float* __restrict__ out)
{
    __shared__ float4       RtE[4][56];              // exp'ed rotation terms per wave
    __shared__ unsigned int ptile[4][1600];          // [wave][((k&15)*50 + k>>4)*2 + pair]
    __shared__ float        ovs[4][4][16];           // [wave(h4)][g][m]

    const int t    = threadIdx.x;
    const int wave = t >> 6, lane = t & 63;
    // XCD-aware decode: low bits round-robin (b, ij-parity) across XCDs
    const int bid = blockIdx.x;
    const int b   = (bid >> 1) & 3;
    const int r   = bid >> 3;
    const int hg  = r & 1;
    const int ij  = (r >> 1) * 2 + (bid & 1);
    const int iq  = ij / WDIM, jq = ij % WDIM;
    const int h   = hg * 4 + wave;
    const int bh  = b * 8 + h;
    const float scale = 0.57735026918962576f;        // 1/sqrt(CIN=3)

    // q in registers (wave-uniform loads, L2-hot)
    float q[16];
    {
        const float4* qp = (const float4*)(Q + (size_t)(bh * NPOS + ij) * 16);
        float4 q0 = qp[0], q1 = qp[1], q2 = qp[2], q3 = qp[3];
        q[0]=q0.x; q[1]=q0.y; q[2]=q0.z; q[3]=q0.w;
        q[4]=q1.x; q[5]=q1.y; q[6]=q1.z; q[7]=q1.w;
        q[8]=q2.x; q[9]=q2.y; q[10]=q2.z; q[11]=q2.w;
        q[12]=q3.x; q[13]=q3.y; q[14]=q3.z; q[15]=q3.w;
    }

    // rotation terms from global tables -> exp'ed
    {
        float4 mine = make_float4(-3.0e38f, -3.0e38f, -3.0e38f, -3.0e38f);
        float4 rv   = mine;
        if (lane < 55) {
            float ar = 0, ac = 0, ar5 = 0, ac5 = 0;
#pragma unroll
            for (int mm = 0; mm < 8; ++mm) {
                float ql = q[mm], qh = q[8 + mm];
                ar  += ql * Etr[mm * 110 + lane];
                ar5 += ql * Etr[mm * 110 + lane + 55];
                ac  += qh * Etc[mm * 110 + lane];
                ac5 += qh * Etc[mm * 110 + lane + 55];
            }
            rv = make_float4(ar * scale, ac * scale, ar5 * scale, ac5 * scale);
            mine = rv;
        }
#pragma unroll
        for (int off = 1; off < 64; off <<= 1) {
            mine.x = fmaxf(mine.x, __shfl_xor(mine.x, off, 64));
            mine.y = fmaxf(mine.y, __shfl_xor(mine.y, off, 64));
            mine.z = fmaxf(mine.z, __shfl_xor(mine.z, off, 64));
            mine.w = fmaxf(mine.w, __shfl_xor(mine.w, off, 64));
        }
        if (lane < 55)
            RtE[wave][lane] = make_float4(__expf(rv.x - mine.x), __expf(rv.y - mine.y),
                                          __expf(rv.z - mine.z), __expf(rv.w - mine.w));
    }

    // pass A: content in registers; track max
    float creg[13];
    float maxc = -3.0e38f;
#pragma unroll
    for (int it = 0; it < 13; ++it) {
        int k = it * 64 + lane;
        creg[it] = 0.0f;
        if (k < NPOS) {
            const float4* kp = (const float4*)(K + (size_t)(bh * NPOS + k) * 16);
            float4 k0 = kp[0], k1 = kp[1], k2 = kp[2], k3 = kp[3];
            float c = q[0]*k0.x + q[1]*k0.y + q[2]*k0.z + q[3]*k0.w
                    + q[4]*k1.x + q[5]*k1.y + q[6]*k1.z + q[7]*k1.w
                    + q[8]*k2.x + q[9]*k2.y + q[10]*k2.z + q[11]*k2.w
                    + q[12]*k3.x + q[13]*k3.y + q[14]*k3.z + q[15]*k3.w;
            creg[it] = c * scale;
            maxc = fmaxf(maxc, creg[it]);
        }
    }
#pragma unroll
    for (int off = 1; off < 64; off <<= 1) maxc = fmaxf(maxc, __shfl_xor(maxc, off, 64));

    // pass B: p once per (key,g); ps accumulated HERE from register p;
    // adjacent f16x2 pairs -> one b64 read per key in pass C.
    float ps0 = 0, ps1 = 0, ps2 = 0, ps3 = 0;
#pragma unroll
    for (int it = 0; it < 13; ++it) {
        int k = it * 64 + lane;
        if (k < NPOS) {
            float ec = __expf(creg[it] - maxc);
            int rk = (k * 2341) >> 16;               // k / 28 (exact for k < 784)
            int ck = k - rk * WDIM;
            float4 er = RtE[wave][rk - iq + 27];
            float4 el = RtE[wave][ck - jq + 27];
            float p0 = ec * er.x * el.y;
            float p1 = ec * er.y * el.z;
            float p2 = ec * er.z * el.w;
            float p3 = ec * er.w * el.x;
            ps0 += p0; ps1 += p1; ps2 += p2; ps3 += p3;
            __half2 h01 = __floats2half2_rn(p0, p1);
            __half2 h23 = __floats2half2_rn(p2, p3);
            int slot = ((k & 15) * 50 + (k >> 4)) * 2;
            ptile[wave][slot]     = *(unsigned int*)&h01;
            ptile[wave][slot + 1] = *(unsigned int*)&h23;
        }
    }
#pragma unroll
    for (int off = 1; off < 64; off <<= 1) {
        ps0 += __shfl_xor(ps0, off, 64); ps1 += __shfl_xor(ps1, off, 64);
        ps2 += __shfl_xor(ps2, off, 64); ps3 += __shfl_xor(ps3, off, 64);
    }

    // pass C (PV): lane = (vq = lane>>4, ch = lane&15); keys k = s*16+ch.
    // one ds_read_b64 + 4 cvt + 16 FMA per key; acc-only reduction.
    {
        const int vq = lane >> 4, ch = lane & 15;
        const unsigned int* pw = &ptile[wave][ch * 100];
        float acc[4][4];
#pragma unroll
        for (int g = 0; g < 4; ++g)
#pragma unroll
            for (int c = 0; c < 4; ++c) acc[g][c] = 0.0f;
#pragma unroll 4
        for (int s = 0; s < 49; ++s) {
            uint2 u2 = *(const uint2*)(pw + s * 2);  // ds_read_b64, 2-way alias = free
            float2 P01 = __half22float2(*(__half2*)&u2.x);
            float2 P23 = __half22float2(*(__half2*)&u2.y);
            float p0 = P01.x, p1 = P01.y, p2 = P23.x, p3 = P23.y;
            int k = s * 16 + ch;
            float4 v = ((const float4*)(V + (size_t)(bh * NPOS + k) * 16))[vq];
            acc[0][0] += p0*v.x; acc[0][1] += p0*v.y; acc[0][2] += p0*v.z; acc[0][3] += p0*v.w;
            acc[1][0] += p1*v.x; acc[1][1] += p1*v.y; acc[1][2] += p1*v.z; acc[1][3] += p1*v.w;
            acc[2][0] += p2*v.x; acc[2][1] += p2*v.y; acc[2][2] += p2*v.z; acc[2][3] += p2*v.w;
            acc[3][0] += p3*v.x; acc[3][1] += p3*v.y; acc[3][2] += p3*v.z; acc[3][3] += p3*v.w;
        }
        // reduce acc over the 16 ch lanes (xor stays within each vq group)
#pragma unroll
        for (int off = 1; off < 16; off <<= 1) {
#pragma unroll
            for (int g = 0; g < 4; ++g)
#pragma unroll
                for (int c = 0; c < 4; ++c) acc[g][c] += __shfl_xor(acc[g][c], off, 64);
        }
        if (ch == 0) {
            float inv0 = 1.0f / ps0, inv1 = 1.0f / ps1, inv2 = 1.0f / ps2, inv3 = 1.0f / ps3;
#pragma unroll
            for (int c = 0; c < 4; ++c) {
                ovs[wave][0][vq * 4 + c] = acc[0][c] * inv0;
                ovs[wave][1][vq * 4 + c] = acc[1][c] * inv1;
                ovs[wave][2][vq * 4 + c] = acc[2][c] * inv2;
                ovs[wave][3][vq * 4 + c] = acc[3][c] * inv3;
            }
        }
    }
    __syncthreads();                                 // this block's 4 heads ready

    // partial output projection over 4 heads; thread = (o = t>>2, g = t&3)
    {
        int o = t >> 2, g = t & 3;
        float a = 0.0f;
#pragma unroll
        for (int m = 0; m < 16; ++m) {
            float4 w4 = *(const float4*)(w_out + o * 128 + m * 8 + hg * 4);
            a += w4.x * ovs[0][g][m] + w4.y * ovs[1][g][m]
               + w4.z * ovs[2][g][m] + w4.w * ovs[3][g][m];
        }
        atomicAdd(out + ((size_t)(b * 64 + o) * 4 + g) * NPOS + ij, a);
    }
}

extern "C" void kernel_launch(void* const* d_in, const int* in_sizes, int n_in,
                              void* d_out, int out_size, void* d_ws, size_t ws_size,
                              hipStream_t stream)
{
    const float* x     = (const float*)d_in[0];
    const float* wq    = (const float*)d_in[1];
    const float* bq    = (const float*)d_in[2];
    const float* wk    = (const float*)d_in[3];
    const float* bk    = (const float*)d_in[4];
    const float* wv    = (const float*)d_in[5];
    const float* bv    = (const float*)d_in[6];
    const float* w_out = (const float*)d_in[7];
    const float* b_out = (const float*)d_in[8];
    const float* rw1 = (const float*)d_in[9];
    const float* rb1 = (const float*)d_in[10];
    const float* rga = (const float*)d_in[11];
    const float* rbe = (const float*)d_in[12];
    const float* rw2 = (const float*)d_in[13];
    const float* rb2 = (const float*)d_in[14];
    const float* cw1 = (const float*)d_in[15];
    const float* cb1 = (const float*)d_in[16];
    const float* cga = (const float*)d_in[17];
    const float* cbe = (const float*)d_in[18];
    const float* cw2 = (const float*)d_in[19];
    const float* cb2 = (const float*)d_in[20];
    // d_in[21]/d_in[22] (ridx/cidx) unused: closed-form rotation indices.

    float* Q   = (float*)d_ws;               // 3 x 401408 floats = 4.8 MB (proven)
    float* K   = Q + 401408;
    float* V   = K + 401408;
    float* Etr = V + 401408;                 // 880 floats
    float* Etc = Etr + 880;                  // 880 floats

    prep_kernel<<<1569, 256, 0, stream>>>(x, wq, bq, wk, bk, wv, bv, b_out,
                                          rw1, rb1, rga, rbe, rw2, rb2,
                                          cw1, cb1, cga, cbe, cw2, cb2,
                                          Q, K, V, Etr, Etc, (float*)d_out);
    attn_kernel<<<8 * NPOS, 256, 0, stream>>>(
        Q, K, V, Etr, Etc, w_out, (float*)d_out);
}